// Round 12
// baseline (243.896 us; speedup 1.0000x reference)
//
#include <hip/hip_runtime.h>
#include <hip/hip_bf16.h>

#define SEQ   2048
#define NH    12
#define MTOK  8192   // 4*2048 token rows

typedef __attribute__((ext_vector_type(8))) short short8;
typedef __attribute__((ext_vector_type(4))) short short4v;
typedef __attribute__((ext_vector_type(4))) float f32x4;

__device__ inline short f2bf(float x) {
  __hip_bfloat16 h = __float2bfloat16(x);
  return *(short*)&h;
}

#define GLL(gp, lp) __builtin_amdgcn_global_load_lds( \
    (const __attribute__((address_space(1))) void*)(gp), \
    (__attribute__((address_space(3))) void*)(lp), 16, 0, 0)

#define MFMA(a, b, c) __builtin_amdgcn_mfma_f32_16x16x32_bf16(a, b, c, 0, 0, 0)

// K=16 bf16 MFMA — device-pass hedge; host pass only parses, give it a stub
#if !defined(__HIP_DEVICE_COMPILE__)
#define MFMA16(a, b, c) (c)
#elif __has_builtin(__builtin_amdgcn_mfma_f32_16x16x16bf16_1k)
#define MFMA16(a, b, c) __builtin_amdgcn_mfma_f32_16x16x16bf16_1k(a, b, c, 0, 0, 0)
#elif __has_builtin(__builtin_amdgcn_mfma_f32_16x16x16_bf16)
#define MFMA16(a, b, c) __builtin_amdgcn_mfma_f32_16x16x16_bf16(a, b, c, 0, 0, 0)
#else
#error "no 16x16x16 bf16 mfma builtin on device"
#endif

// native exp2 (1 VALU op) hedge
#if !defined(__HIP_DEVICE_COMPILE__)
#define EXP2(x) (x)
#elif __has_builtin(__builtin_amdgcn_exp2f)
#define EXP2(x) __builtin_amdgcn_exp2f(x)
#else
#define EXP2(x) __expf((x) * 0.6931471805599453f)
#endif

// pack two fp32 -> bf16x2 dword (round-half-away; inputs finite)
__device__ inline unsigned pack2bf(float a, float b) {
  unsigned ua = __float_as_uint(a) + 0x8000u;
  unsigned ub = __float_as_uint(b) + 0x8000u;
#if defined(__HIP_DEVICE_COMPILE__) && __has_builtin(__builtin_amdgcn_perm)
  return __builtin_amdgcn_perm(ub, ua, 0x07060302u);
#else
  return (ub & 0xFFFF0000u) | (ua >> 16);
#endif
}

union PackFrag {
  unsigned u[2];
  short4v s;
};

// log2(e)*0.125 folded into Q so p = exp2(S + maskbias)
#define QSCALE 0.18033688011112042f
#define MBSCALE -14426.950408889634f  // -10000*log2(e)

// ---------------------------------------------------------------------------
// Fused prep: hs->Xb bf16 | Wq|Wk|Wv->Wqkvb, Wo->Wob | mask->mbias
// ---------------------------------------------------------------------------
__global__ __launch_bounds__(256) void prep(
    const float* __restrict__ hs, const float* __restrict__ Wq,
    const float* __restrict__ Wk, const float* __restrict__ Wv,
    const float* __restrict__ Wo, const float* __restrict__ mask,
    short* __restrict__ Xb, short* __restrict__ Wqkvb,
    short* __restrict__ Wob, float* __restrict__ mbias) {
  int bid = blockIdx.x;
  if (bid < 6144) {
    int i = bid * 256 + threadIdx.x;     // 8192*192 float4s
    float4 v = ((const float4*)hs)[i];
    short4v o;
    o[0] = f2bf(v.x); o[1] = f2bf(v.y); o[2] = f2bf(v.z); o[3] = f2bf(v.w);
    ((short4v*)Xb)[i] = o;
  } else if (bid < 6144 + 2304) {
    int idx = (bid - 6144) * 256 + threadIdx.x;  // 3072*192
    int r = idx / 192, c = (idx - r * 192) * 4;
    const float* src;
    short* dst;
    int rr;
    if (r < 768)       { src = Wq; rr = r;        dst = Wqkvb; }
    else if (r < 1536) { src = Wk; rr = r - 768;  dst = Wqkvb; }
    else if (r < 2304) { src = Wv; rr = r - 1536; dst = Wqkvb; }
    else               { src = Wo; rr = r - 2304; dst = Wob; r = rr; }
    float4 v = *(const float4*)&src[(size_t)rr * 768 + c];
    short4v o;
    o[0] = f2bf(v.x); o[1] = f2bf(v.y); o[2] = f2bf(v.z); o[3] = f2bf(v.w);
    *(short4v*)&dst[(size_t)r * 768 + c] = o;
  } else {
    int i = (bid - 6144 - 2304) * 256 + threadIdx.x;
    if (i < MTOK) mbias[i] = (1.f - mask[i]) * MBSCALE;
  }
}

// ---------------------------------------------------------------------------
// BK=64 GEMM core (r10, unchanged): 128x128 tile, XOR-chunk-swizzled LDS.
// ---------------------------------------------------------------------------
#define GEMM_BK64_LOOP(Aptr, Bptr)                                            \
  __shared__ __align__(16) short As[128 * 64];                                \
  __shared__ __align__(16) short Bs[128 * 64];                                \
  const int t = threadIdx.x;                                                  \
  const int wid = t >> 6, lane = t & 63, l15 = lane & 15, quad = lane >> 4;   \
  const int bm = blockIdx.x * 128, bn = blockIdx.y * 128;                     \
  const int mq = (wid & 1) * 64, nq = (wid >> 1) * 64;                        \
  const int srow8 = lane >> 3;                                                \
  const int schunk = lane & 7;                                                \
  const int scol = (schunk ^ srow8) * 8;                                      \
  f32x4 acc[4][4] = {};                                                       \
  const short *gA[4], *gB[4];                                                 \
  _Pragma("unroll") for (int g = 0; g < 4; ++g) {                             \
    int row = wid * 32 + g * 8 + srow8;                                       \
    gA[g] = (Aptr) + (size_t)(bm + row) * 768 + scol;                         \
    gB[g] = (Bptr) + (size_t)(bn + row) * 768 + scol;                         \
  }                                                                           \
  for (int k0 = 0; k0 < 768; k0 += 64) {                                      \
    _Pragma("unroll") for (int g = 0; g < 4; ++g)                             \
      GLL(gA[g] + k0, &As[(wid * 32 + g * 8) * 64]);                          \
    _Pragma("unroll") for (int g = 0; g < 4; ++g)                             \
      GLL(gB[g] + k0, &Bs[(wid * 32 + g * 8) * 64]);                          \
    __syncthreads();                                                          \
    _Pragma("unroll") for (int ks = 0; ks < 2; ++ks) {                        \
      short8 a[4], b[4];                                                      \
      _Pragma("unroll") for (int mt = 0; mt < 4; ++mt)                        \
        a[mt] = *(const short8*)&As[(mq + mt * 16 + l15) * 64 +               \
                                    (((ks * 4 + quad) ^ (l15 & 7)) * 8)];     \
      _Pragma("unroll") for (int nt = 0; nt < 4; ++nt)                        \
        b[nt] = *(const short8*)&Bs[(nq + nt * 16 + l15) * 64 +               \
                                    (((ks * 4 + quad) ^ (l15 & 7)) * 8)];     \
      _Pragma("unroll") for (int mt = 0; mt < 4; ++mt)                        \
        _Pragma("unroll") for (int nt = 0; nt < 4; ++nt)                      \
          acc[mt][nt] = MFMA(a[mt], b[nt], acc[mt][nt]);                      \
    }                                                                         \
    __syncthreads();                                                          \
  }

// ---------------------------------------------------------------------------
__global__ __launch_bounds__(256) void gemm_qkv(
    const short* __restrict__ A, const short* __restrict__ B,
    const float* __restrict__ bq, const float* __restrict__ bk,
    const float* __restrict__ bv, short* __restrict__ Qb,
    short* __restrict__ Kb, short* __restrict__ Vt) {
  GEMM_BK64_LOOP(A, B)

  const int seg = bn >= 1536 ? 2 : (bn >= 768 ? 1 : 0);
  const float* bias = seg == 0 ? bq : (seg == 1 ? bk : bv);
  const int colbase = bn - seg * 768;

  if (seg < 2) {
    short* dst = seg == 0 ? Qb : Kb;
    const float sc = seg == 0 ? QSCALE : 1.f;
#pragma unroll
    for (int mt = 0; mt < 4; ++mt)
#pragma unroll
      for (int nt = 0; nt < 4; ++nt) {
        int col = colbase + nq + nt * 16 + l15;
        float bias_v = bias[col];
#pragma unroll
        for (int i = 0; i < 4; ++i) {
          int row = bm + mq + mt * 16 + quad * 4 + i;
          dst[(size_t)row * 768 + col] = f2bf((acc[mt][nt][i] + bias_v) * sc);
        }
      }
  } else {
#pragma unroll
    for (int mt = 0; mt < 4; ++mt) {
      int row0 = bm + mq + mt * 16 + quad * 4;
      int b_ = row0 >> 11, s = row0 & 2047;
#pragma unroll
      for (int nt = 0; nt < 4; ++nt) {
        int col = colbase + nq + nt * 16 + l15;
        float bias_v = bias[col];
        int h = col >> 6, d = col & 63;
        short4v pv;
#pragma unroll
        for (int i = 0; i < 4; ++i) pv[i] = f2bf(acc[mt][nt][i] + bias_v);
        *(short4v*)&Vt[(((size_t)b_ * NH + h) * 64 + d) * 2048 + s] = pv;
      }
    }
  }
}

// ---------------------------------------------------------------------------
__global__ __launch_bounds__(256) void gemm_out(
    const short* __restrict__ A, const short* __restrict__ B,
    const float* __restrict__ bias, float* __restrict__ C) {
  GEMM_BK64_LOOP(A, B)

#pragma unroll
  for (int mt = 0; mt < 4; ++mt)
#pragma unroll
    for (int nt = 0; nt < 4; ++nt) {
      int col = bn + nq + nt * 16 + l15;
      float bias_v = bias[col];
#pragma unroll
      for (int i = 0; i < 4; ++i) {
        int row = bm + mq + mt * 16 + quad * 4 + i;
        C[(size_t)row * 768 + col] = acc[mt][nt][i] + bias_v;
      }
    }
}

// ---------------------------------------------------------------------------
// attn_v9: r9 structure with qtile=64 -> 1536 blocks = 6 blocks/CU
// (TLP doubled; r11 cycle-count showed 3 waves/SIMD left kernel ~75%
// dependency-stalled). Wave owns 16 q rows. Single-buffer LDS 16KB,
// 2 barriers/tile. Register-resident P (S^T trick), l via ones-MFMA.
// ---------------------------------------------------------------------------
__global__ __launch_bounds__(256, 6) void attn_v9(
    const short* __restrict__ Qb, const short* __restrict__ Kb,
    const short* __restrict__ Vt, const float* __restrict__ maskb,
    short* __restrict__ Ctx) {
  __shared__ __align__(16) short Ks[64 * 64];   // [key][dchunk^swz]
  __shared__ __align__(16) short Vs[64 * 64];   // [d][keychunk^swz]
  const int t = threadIdx.x;
  const int w = t >> 6, lane = t & 63, l15 = lane & 15, quad = lane >> 4;
  const int bh = blockIdx.x, b = bh / NH, h = bh % NH;
  const int q0 = blockIdx.y * 64;

  // Q fragments (pre-scaled by QSCALE): wave owns rows q0+w*16 .. +16
  short8 qa[2];
#pragma unroll
  for (int ks = 0; ks < 2; ++ks) {
    int row = b * 2048 + q0 + w * 16 + l15;
    qa[ks] = *(const short8*)&Qb[(size_t)row * 768 + h * 64 + ks * 32 + quad * 8];
  }

  f32x4 O[4] = {};     // O^T tiles [dt], D[m=d][n=q]
  f32x4 lacc = {};     // l[q] replicated across rows
  short4v ones4;
#pragma unroll
  for (int j = 0; j < 4; ++j) ones4[j] = (short)0x3F80;  // bf16 1.0

  // GLL staging: wave w stages rows [w*16, w*16+16) of K and V tiles
  const int r0 = w * 16 + (lane >> 3);
  const int pc = lane & 7;
  const int swz0 = (pc ^ (r0 & 7)) * 8;
  const int swz1 = (pc ^ ((r0 + 8) & 7)) * 8;
  const short* gK0 = Kb + (size_t)(b * 2048 + r0) * 768 + h * 64 + swz0;
  const short* gK1 = Kb + (size_t)(b * 2048 + r0 + 8) * 768 + h * 64 + swz1;
  const short* gV0 = Vt + ((size_t)bh * 64 + r0) * 2048 + swz0;
  const short* gV1 = Vt + ((size_t)bh * 64 + r0 + 8) * 2048 + swz1;
  const float* mb = maskb + b * 2048;
  const int rs = l15 & 7;  // read-side swizzle key

  for (int k0 = 0; k0 < SEQ; k0 += 64) {
    GLL(gK0 + (size_t)k0 * 768, &Ks[(w * 16) * 64]);
    GLL(gK1 + (size_t)k0 * 768, &Ks[(w * 16 + 8) * 64]);
    GLL(gV0 + k0, &Vs[(w * 16) * 64]);
    GLL(gV1 + k0, &Vs[(w * 16 + 8) * 64]);
    __syncthreads();

    // S^T[kt] = K.Q^T   (rows=key, cols=q)
    f32x4 S[4] = {};
#pragma unroll
    for (int ks = 0; ks < 2; ++ks) {
      short8 kb[4];
#pragma unroll
      for (int kt = 0; kt < 4; ++kt)
        kb[kt] = *(const short8*)&Ks[(kt * 16 + l15) * 64 +
                                     (((ks * 4 + quad) ^ rs) * 8)];
#pragma unroll
      for (int kt = 0; kt < 4; ++kt)
        S[kt] = MFMA(kb[kt], qa[ks], S[kt]);
    }

    // p = exp2(S^T + maskbias[key]) -> packed bf16 B-fragments (registers)
    short4v pb[4];
#pragma unroll
    for (int kt = 0; kt < 4; ++kt) {
      float4 mb4 = *(const float4*)&mb[k0 + kt * 16 + quad * 4];
      float p0 = EXP2(S[kt][0] + mb4.x);
      float p1 = EXP2(S[kt][1] + mb4.y);
      float p2 = EXP2(S[kt][2] + mb4.z);
      float p3 = EXP2(S[kt][3] + mb4.w);
      PackFrag pf;
      pf.u[0] = pack2bf(p0, p1);
      pf.u[1] = pack2bf(p2, p3);
      pb[kt] = pf.s;
    }

    // l += P.1
#pragma unroll
    for (int kt = 0; kt < 4; ++kt)
      lacc = MFMA16(ones4, pb[kt], lacc);

    // O^T += V^T.P^T : A = V^T[d][key-chunk] (ds_read_b64), B = pb
#pragma unroll
    for (int kt = 0; kt < 4; ++kt) {
#pragma unroll
      for (int dt = 0; dt < 4; ++dt) {
        short4v av = *(const short4v*)&Vs[(dt * 16 + l15) * 64 +
            (((kt * 2 + (quad >> 1)) ^ rs) * 8) + (quad & 1) * 4];
        O[dt] = MFMA16(av, pb[kt], O[dt]);
      }
    }
    __syncthreads();
  }

  // epilogue: lane holds O^T[d=quad*4+i][q=l15]; l[q] = lacc[any]
  {
    float inv = 1.f / lacc[0];
    int row = b * 2048 + q0 + w * 16 + l15;
#pragma unroll
    for (int dt = 0; dt < 4; ++dt) {
      PackFrag pf;
      pf.u[0] = pack2bf(O[dt][0] * inv, O[dt][1] * inv);
      pf.u[1] = pack2bf(O[dt][2] * inv, O[dt][3] * inv);
      *(short4v*)&Ctx[(size_t)row * 768 + h * 64 + dt * 16 + quad * 4] = pf.s;
    }
  }
}

// ---------------------------------------------------------------------------
extern "C" void kernel_launch(void* const* d_in, const int* in_sizes, int n_in,
                              void* d_out, int out_size, void* d_ws,
                              size_t ws_size, hipStream_t stream) {
  const float* hs   = (const float*)d_in[0];
  const float* mask = (const float*)d_in[1];
  const float* Wq   = (const float*)d_in[2];
  const float* bq   = (const float*)d_in[3];
  const float* Wk   = (const float*)d_in[4];
  const float* bk   = (const float*)d_in[5];
  const float* Wv   = (const float*)d_in[6];
  const float* bv   = (const float*)d_in[7];
  const float* Wo   = (const float*)d_in[8];
  const float* bo   = (const float*)d_in[9];

  char* ws = (char*)d_ws;
  short* Xb    = (short*)(ws);               // 8192x768  bf16  12.58MB
  short* Wqkvb = (short*)(ws + 12582912);    // 2304x768  bf16   3.54MB
  short* Wob   = (short*)(ws + 16121856);    // 768x768   bf16   1.18MB
  short* Qb    = (short*)(ws + 17301504);    // 8192x768  bf16  12.58MB
  short* Kb    = (short*)(ws + 29884416);    // 8192x768  bf16  12.58MB
  short* Vtg   = (short*)(ws + 42467328);    // [4][12][64][2048] 12.58MB
  short* Ctxb  = (short*)(ws + 55050240);    // 8192x768  bf16  12.58MB
  float* mbias = (float*)(ws + 67633152);    // 8192 f32  32KB

  prep<<<8480, 256, 0, stream>>>(hs, Wq, Wk, Wv, Wo, mask,
                                 Xb, Wqkvb, Wob, mbias);
  gemm_qkv<<<dim3(64, 18), 256, 0, stream>>>(Xb, Wqkvb, bq, bk, bv,
                                             Qb, Kb, Vtg);
  attn_v9<<<dim3(48, 32), 256, 0, stream>>>(Qb, Kb, Vtg, mbias, Ctxb);
  gemm_out<<<dim3(64, 6), 256, 0, stream>>>(Ctxb, Wob, bo, (float*)d_out);
}